// Round 12
// baseline (190.872 us; speedup 1.0000x reference)
//
#include <hip/hip_runtime.h>
#include <hip/hip_bf16.h>
#include <stdint.h>
#include <type_traits>

// MoE (E=16, D=1024, H=2048, K=2, T=2048), routed bf16-MFMA.
// R12 = R9 (best: 147us) with the per-K-step sync cost HALVED:
// 3 LDS buffers -> ONE s_barrier + ONE counted vmcnt wait per step
// (R9 had 2 barriers + 2 waits + 2 lgkm drains). Schedule per step t:
//   waitv8(tile t's 8 vmem done) ; writeB(t) ; lgkm0+barrier ;
//   issue A/B(t+2) into slot (t+2)%3 (freed: all waves passed compute(t-1)) ;
//   compute(t).
// B weight loads are nontemporal (read-once). LDS 75KB -> 2 blocks/CU
// (R11 proved occupancy is not the lever; barrier count is).

#define E_ 16
#define D_ 1024
#define H_ 2048
#define K_ 2
#define T_ 2048
#define NP_ (T_ * K_)     // 4096 token-expert pairs
#define MTS_ 48           // max M-tiles: sum ceil(ne/128) <= 48

using short8 = __attribute__((ext_vector_type(8))) short;
using f32x4  = __attribute__((ext_vector_type(4))) float;

__device__ __forceinline__ unsigned short f2bf(float f) {
  union { float f; unsigned u; } x; x.f = f;
  unsigned r = x.u + 0x7fffu + ((x.u >> 16) & 1u);   // RNE
  return (unsigned short)(r >> 16);
}

// gelu(tanh approx) = x * sigmoid(1.595769...*(x + 0.044715 x^3))
__device__ __forceinline__ float gelu_f(float x) {
  float u = 1.5957691216057308f * (x + 0.044715f * x * x * x);
  return x / (1.f + __expf(-u));
}

__device__ __forceinline__ void waitv8() {
  asm volatile("s_waitcnt vmcnt(8)" ::: "memory");
  __builtin_amdgcn_sched_barrier(0);
}
__device__ __forceinline__ void waitv0() {
  asm volatile("s_waitcnt vmcnt(0)" ::: "memory");
  __builtin_amdgcn_sched_barrier(0);
}
__device__ __forceinline__ void lgkm0_barrier() {
  asm volatile("s_waitcnt lgkmcnt(0)" ::: "memory");
  __builtin_amdgcn_sched_barrier(0);
  __builtin_amdgcn_s_barrier();
  __builtin_amdgcn_sched_barrier(0);
}

__global__ void cvt_kernel(const float* __restrict__ src,
                           unsigned short* __restrict__ dst, int n4) {
  int stride = gridDim.x * blockDim.x;
  for (int i = blockIdx.x * blockDim.x + threadIdx.x; i < n4; i += stride) {
    float4 v = reinterpret_cast<const float4*>(src)[i];
    ushort4 o = make_ushort4(f2bf(v.x), f2bf(v.y), f2bf(v.z), f2bf(v.w));
    reinterpret_cast<ushort4*>(dst)[i] = o;
  }
}

__global__ void route_kernel(const int* __restrict__ gidx,
                             int* __restrict__ rows,
                             int* __restrict__ offsets,
                             int2* __restrict__ tiles) {
  __shared__ int cnt[E_], cur[E_];
  int tid = threadIdx.x;
  if (tid < E_) cnt[tid] = 0;
  __syncthreads();
  for (int p = tid; p < NP_; p += blockDim.x) atomicAdd(&cnt[gidx[p]], 1);
  __syncthreads();
  if (tid == 0) {
    int acc = 0;
    for (int e = 0; e < E_; ++e) { offsets[e] = acc; cur[e] = acc; acc += cnt[e]; }
    offsets[E_] = acc;
    int k = 0;
    for (int e = 0; e < E_; ++e)
      for (int m = offsets[e]; m < offsets[e] + cnt[e]; m += 128)
        tiles[k++] = make_int2(e, m);
    for (; k < MTS_; ++k) tiles[k] = make_int2(-1, 0);
  }
  __syncthreads();
  for (int p = tid; p < NP_; p += blockDim.x) {
    int e = gidx[p];
    int pos = atomicAdd(&cur[e], 1);
    rows[pos] = p;
  }
}

#define GLOAD16(g, l)                                                        \
  __builtin_amdgcn_global_load_lds(                                          \
      (const __attribute__((address_space(1))) unsigned int*)(const void*)(g), \
      (__attribute__((address_space(3))) unsigned int*)(void*)(l), 16, 0, 0)

// NT GEMM: 128(M)x64(N)x64(K) tile, 4 waves as 2x2 (each 64x32).
// A (bf16) via global_load_lds, source-side XOR swizzle (verified R2-R9).
// B (f32) reg-staged line-efficient + nontemporal, cvt bf16, ds_write
// XOR-swizzled (R9 mapping, verified).
template<bool IS1>
__global__ __launch_bounds__(256, 2)
void moe_gemm(const unsigned short* __restrict__ A0,   // xb (IS1) or h
              const float* __restrict__ W,             // w1 or w2 (f32)
              const float* __restrict__ bias,          // b1 or b2  [E][NN]
              const int* __restrict__ rows,
              const int* __restrict__ offsets,
              const int2* __restrict__ tiles,
              const float* __restrict__ score,         // [T*K]
              unsigned short* __restrict__ Hout,       // h (IS1)
              float* __restrict__ Yout)                // y (!IS1)
{
  constexpr int BM = 128, BN = 64, BK = 64;
  constexpr int KD = IS1 ? D_ : H_;   // contraction dim
  constexpr int NN = IS1 ? H_ : D_;   // output cols
  constexpr int NT = KD / BK;         // 16 or 32

  const int2 tile = tiles[blockIdx.y];
  const int e = tile.x;
  if (e < 0) return;
  const int s0   = tile.y;
  const int send = offsets[e + 1];
  const int n0   = blockIdx.x * BN;

  __shared__ unsigned short As[3][BM][BK];   // XOR-slot swizzled
  __shared__ unsigned short Bs[3][BN][BK];   // XOR-slot swizzled
  __shared__ int rowsrc[BM];
  __shared__ int rowdst[BM];

  const int tid  = threadIdx.x;
  const int lane = tid & 63;
  const int wid  = tid >> 6;

  if (tid < BM) {
    int s = s0 + tid;
    bool v = s < send;
    int sc2 = v ? s : s0;
    if (IS1) {
      rowsrc[tid] = rows[sc2] >> 1;   // token id (K_=2)
      rowdst[tid] = v ? s : -1;       // h row (routed order)
    } else {
      rowsrc[tid] = sc2;              // h row
      rowdst[tid] = v ? rows[s] : -1; // pair id for scatter + score
    }
  }
  __syncthreads();

  // A staging: per wave 4 x global_load_lds(16B), 8 rows each; LDS dest
  // linear, SOURCE slot pre-XOR'd: LDS[row][s] holds global slot s^(row&7).
  const int arow  = lane >> 3;
  const int aslot = (lane & 7) ^ arow;
  const unsigned short* gA[4];
#pragma unroll
  for (int i = 0; i < 4; ++i)
    gA[i] = A0 + (size_t)rowsrc[wid * 32 + i * 8 + arow] * KD + aslot * 8;

  // B staging, line-efficient: thread t -> row t>>3 (0..31), oct t&7.
  // Each wave-instr = 8 consecutive rows x 128B contiguous (full lines).
  const int brow = tid >> 3, boct = tid & 7;
  const float* gB0 = W + (size_t)e * NN * KD + (size_t)(n0 + brow) * KD + boct * 4;
  const float* gB2 = gB0 + (size_t)32 * KD;

  const int wr = wid >> 1, wc = wid & 1;
  const int fr = lane & 15, fh = lane >> 4;

  f32x4 acc[4][2] = {};
  f32x4 breg0[4], breg1[4], breg2[4];

  auto issueA = [&](int buf, int kk) {
#pragma unroll
    for (int i = 0; i < 4; ++i)
      GLOAD16(gA[i] + kk, &As[buf][wid * 32 + i * 8][0]);
  };
  auto issueB = [&](f32x4* br, int kk) {
    br[0] = __builtin_nontemporal_load(reinterpret_cast<const f32x4*>(gB0 + kk));
    br[1] = __builtin_nontemporal_load(reinterpret_cast<const f32x4*>(gB0 + kk + 32));
    br[2] = __builtin_nontemporal_load(reinterpret_cast<const f32x4*>(gB2 + kk));
    br[3] = __builtin_nontemporal_load(reinterpret_cast<const f32x4*>(gB2 + kk + 32));
  };
  // piece (row, kl0): 4 shorts at swizzled addr; slot=(kl0>>3)^(row&7).
  auto writeB = [&](int buf, const f32x4* br) {
#pragma unroll
    for (int p = 0; p < 4; ++p) {
      int row = (p & 2) ? brow + 32 : brow;
      int kl0 = boct * 4 + ((p & 1) ? 32 : 0);
      ushort4 u;
      u.x = f2bf(br[p][0]); u.y = f2bf(br[p][1]);
      u.z = f2bf(br[p][2]); u.w = f2bf(br[p][3]);
      int idx = (((kl0 >> 3) ^ (row & 7)) << 3) + (kl0 & 7);
      *reinterpret_cast<ushort4*>(&Bs[buf][row][idx]) = u;
    }
  };
  auto compute = [&](int buf) {
    short8 af[4][2], bv[2][2];
#pragma unroll
    for (int mi = 0; mi < 4; ++mi) {
      const int row = wr * 64 + mi * 16 + fr;
#pragma unroll
      for (int ks = 0; ks < 2; ++ks) {
        const int slot = (ks * 4 + fh) ^ (row & 7);
        af[mi][ks] = *reinterpret_cast<const short8*>(&As[buf][row][slot * 8]);
      }
    }
#pragma unroll
    for (int ni = 0; ni < 2; ++ni) {
      const int row = wc * 32 + ni * 16 + fr;
#pragma unroll
      for (int ks = 0; ks < 2; ++ks) {
        const int slot = (ks * 4 + fh) ^ (row & 7);
        bv[ni][ks] = *reinterpret_cast<const short8*>(&Bs[buf][row][slot * 8]);
      }
    }
#pragma unroll
    for (int ks = 0; ks < 2; ++ks)
#pragma unroll
      for (int mi = 0; mi < 4; ++mi)
#pragma unroll
        for (int ni = 0; ni < 2; ++ni)
          acc[mi][ni] = __builtin_amdgcn_mfma_f32_16x16x32_bf16(
              af[mi][ks], bv[ni][ks], acc[mi][ni], 0, 0, 0);
  };

  // Prologue: issue tiles 0,1 (16 vmem ops/wave outstanding).
  issueA(0, 0);       issueB(breg0, 0);
  issueA(1, BK);      issueB(breg1, BK);

  // Steady state, ONE barrier + ONE counted wait per step:
  //   waitv8: tile t's 8 ops done (A in LDS, B in regs)
  //   writeB(t) pre-barrier (slot t%3; nobody reads it yet)
  //   lgkm0+barrier: tile t fully visible; slot (t+2)%3=(t-1)%3 freed
  //   issue tile t+2 ; compute tile t
  auto body = [&](int t, auto Sc) {
    constexpr int S = decltype(Sc)::value;   // t % 3
    f32x4* brCur  = (S == 0) ? breg0 : (S == 1) ? breg1 : breg2;
    f32x4* brNext = (S == 0) ? breg2 : (S == 1) ? breg0 : breg1;  // (S+2)%3
    if (t + 1 < NT) waitv8(); else waitv0();
    writeB(S, brCur);
    lgkm0_barrier();
    if (t + 2 < NT) {
      issueA((S + 2) % 3, (t + 2) * BK);
      issueB(brNext, (t + 2) * BK);
    }
    compute(S);
  };
  for (int t = 0; t < NT; t += 3) {
    body(t, std::integral_constant<int, 0>{});
    if (t + 1 < NT) body(t + 1, std::integral_constant<int, 1>{});
    if (t + 2 < NT) body(t + 2, std::integral_constant<int, 2>{});
  }

  // Epilogue. C/D map: row = (lane>>4)*4 + j, col = lane&15 (m89-verified).
  const float* biasE = bias + (size_t)e * NN + n0;
#pragma unroll
  for (int mi = 0; mi < 4; ++mi) {
#pragma unroll
    for (int j = 0; j < 4; ++j) {
      int rt  = wr * 64 + mi * 16 + fh * 4 + j;
      int dst = rowdst[rt];
      if (dst < 0) continue;
      float sc = IS1 ? 0.f : score[dst];
#pragma unroll
      for (int ni = 0; ni < 2; ++ni) {
        int col = wc * 32 + ni * 16 + fr;
        float v = acc[mi][ni][j] + biasE[col];
        if (IS1) {
          Hout[(size_t)dst * H_ + n0 + col] = f2bf(gelu_f(v));
        } else {
          Yout[(size_t)dst * D_ + n0 + col] = v * sc;
        }
      }
    }
  }
}

__global__ void combine_kernel(const float* __restrict__ y,
                               float* __restrict__ out) {
  const int DQ = D_ / 4;
  int i = blockIdx.x * blockDim.x + threadIdx.x;   // [0, T_*D_/4)
  int t = i / DQ, d = i % DQ;
  const float4* y4 = reinterpret_cast<const float4*>(y);
  float4 a = y4[(size_t)(2 * t) * DQ + d];
  float4 b = y4[(size_t)(2 * t + 1) * DQ + d];
  reinterpret_cast<float4*>(out)[i] =
      make_float4(a.x + b.x, a.y + b.y, a.z + b.z, a.w + b.w);
}

extern "C" void kernel_launch(void* const* d_in, const int* in_sizes, int n_in,
                              void* d_out, int out_size, void* d_ws, size_t ws_size,
                              hipStream_t stream) {
  const float* inp    = (const float*)d_in[0];
  const int*   gidx   = (const int*)d_in[1];
  const float* gscore = (const float*)d_in[2];
  const float* w1     = (const float*)d_in[3];
  const float* b1     = (const float*)d_in[4];
  const float* w2     = (const float*)d_in[5];
  const float* b2     = (const float*)d_in[6];
  float* out = (float*)d_out;

  char* ws = (char*)d_ws;
  size_t o = 0;
  auto alloc = [&](size_t bytes) {
    void* p = ws + o;
    o = (o + bytes + 255) & ~(size_t)255;
    return p;
  };
  unsigned short* xb   = (unsigned short*)alloc((size_t)T_ * D_ * 2);
  unsigned short* hbuf = (unsigned short*)alloc((size_t)NP_ * H_ * 2);
  float*          ybuf = (float*)alloc((size_t)NP_ * D_ * 4);
  int*            rows = (int*)alloc(NP_ * 4);
  int*         offsets = (int*)alloc((E_ + 1) * 4);
  int2*          tiles = (int2*)alloc(MTS_ * 8);

  cvt_kernel<<<dim3(512), dim3(256), 0, stream>>>(inp, xb, T_ * D_ / 4);
  route_kernel<<<dim3(1), dim3(256), 0, stream>>>(gidx, rows, offsets, tiles);

  moe_gemm<true><<<dim3(H_ / 64, MTS_), dim3(256), 0, stream>>>(
      xb, w1, b1, rows, offsets, tiles, gscore, hbuf, (float*)nullptr);
  moe_gemm<false><<<dim3(D_ / 64, MTS_), dim3(256), 0, stream>>>(
      hbuf, w2, b2, rows, offsets, tiles, gscore, (unsigned short*)nullptr, ybuf);

  combine_kernel<<<dim3(T_ * D_ / 4 / 256), dim3(256), 0, stream>>>(ybuf, out);
}

// Round 13
// 159.408 us; speedup vs baseline: 1.1974x; 1.1974x over previous
//
#include <hip/hip_runtime.h>
#include <hip/hip_bf16.h>
#include <stdint.h>
#include <type_traits>

// MoE (E=16, D=1024, H=2048, K=2, T=2048), routed bf16-MFMA.
// R13: minimize (K-steps x per-step-sync-cost / blocks-per-CU).
// BK=32, BM=128, BN=128; ONE s_barrier + ONE vmcnt(2) + ONE lgkm per step.
// As 3-slot (A ahead-by-2 via global_load_lds), Bs 2-slot LDS + breg 2-slot
// (B ahead-by-1, issued pre-barrier). LDS 41KB -> 3 blocks/CU. GEMM2 is
// split-K=2 (592 blocks each GEMM, NT=32 both); partials summed in combine.

#define E_ 16
#define D_ 1024
#define H_ 2048
#define K_ 2
#define T_ 2048
#define NP_ (T_ * K_)     // 4096 token-expert pairs
#define MTS_ 48           // max M-tiles: sum ceil(ne/128) <= 48

using short8 = __attribute__((ext_vector_type(8))) short;
using f32x4  = __attribute__((ext_vector_type(4))) float;

__device__ __forceinline__ unsigned short f2bf(float f) {
  union { float f; unsigned u; } x; x.f = f;
  unsigned r = x.u + 0x7fffu + ((x.u >> 16) & 1u);   // RNE
  return (unsigned short)(r >> 16);
}

// gelu(tanh approx) = x * sigmoid(1.595769...*(x + 0.044715 x^3))
__device__ __forceinline__ float gelu_f(float x) {
  float u = 1.5957691216057308f * (x + 0.044715f * x * x * x);
  return x / (1.f + __expf(-u));
}

__device__ __forceinline__ void waitv2() {
  asm volatile("s_waitcnt vmcnt(2)" ::: "memory");
  __builtin_amdgcn_sched_barrier(0);
}
__device__ __forceinline__ void waitv0() {
  asm volatile("s_waitcnt vmcnt(0)" ::: "memory");
  __builtin_amdgcn_sched_barrier(0);
}
__device__ __forceinline__ void lgkm0_barrier() {
  asm volatile("s_waitcnt lgkmcnt(0)" ::: "memory");
  __builtin_amdgcn_sched_barrier(0);
  __builtin_amdgcn_s_barrier();
  __builtin_amdgcn_sched_barrier(0);
}

__global__ void cvt_kernel(const float* __restrict__ src,
                           unsigned short* __restrict__ dst, int n4) {
  int stride = gridDim.x * blockDim.x;
  for (int i = blockIdx.x * blockDim.x + threadIdx.x; i < n4; i += stride) {
    float4 v = reinterpret_cast<const float4*>(src)[i];
    ushort4 o = make_ushort4(f2bf(v.x), f2bf(v.y), f2bf(v.z), f2bf(v.w));
    reinterpret_cast<ushort4*>(dst)[i] = o;
  }
}

__global__ void route_kernel(const int* __restrict__ gidx,
                             int* __restrict__ rows,
                             int* __restrict__ offsets,
                             int2* __restrict__ tiles) {
  __shared__ int cnt[E_], cur[E_];
  int tid = threadIdx.x;
  if (tid < E_) cnt[tid] = 0;
  __syncthreads();
  for (int p = tid; p < NP_; p += blockDim.x) atomicAdd(&cnt[gidx[p]], 1);
  __syncthreads();
  if (tid == 0) {
    int acc = 0;
    for (int e = 0; e < E_; ++e) { offsets[e] = acc; cur[e] = acc; acc += cnt[e]; }
    offsets[E_] = acc;
    int k = 0;
    for (int e = 0; e < E_; ++e)
      for (int m = offsets[e]; m < offsets[e] + cnt[e]; m += 128)
        tiles[k++] = make_int2(e, m);
    for (; k < MTS_; ++k) tiles[k] = make_int2(-1, 0);
  }
  __syncthreads();
  for (int p = tid; p < NP_; p += blockDim.x) {
    int e = gidx[p];
    int pos = atomicAdd(&cur[e], 1);
    rows[pos] = p;
  }
}

#define GLOAD16(g, l)                                                        \
  __builtin_amdgcn_global_load_lds(                                          \
      (const __attribute__((address_space(1))) unsigned int*)(const void*)(g), \
      (__attribute__((address_space(3))) unsigned int*)(void*)(l), 16, 0, 0)

template<int N> using ic = std::integral_constant<int, N>;

// NT GEMM: 128(M)x128(N)x32(K) tile, 4 waves as 2x2 (each 64x64).
// A (bf16 acts) via global_load_lds, R11-verified source swizzle.
// B (f32 weights) reg-staged full-line, cvt bf16, ds_write swizzled.
template<bool IS1>
__global__ __launch_bounds__(256, 3)
void moe_gemm(const unsigned short* __restrict__ A0,   // xb (IS1) or h
              const float* __restrict__ W,             // w1 or w2 (f32)
              const float* __restrict__ bias,          // b1 or b2  [E][NN]
              const int* __restrict__ rows,
              const int* __restrict__ offsets,
              const int2* __restrict__ tiles,
              const float* __restrict__ score,         // [T*K] (unused IS1)
              unsigned short* __restrict__ Hout,       // h (IS1)
              float* __restrict__ Yout)                // ypart (!IS1)
{
  constexpr int BM = 128, BN = 128, BK = 32;
  constexpr int KD = IS1 ? D_ : H_;   // full contraction dim (row stride)
  constexpr int NN = IS1 ? H_ : D_;   // output cols
  constexpr int NT = 32;              // K-steps: 1024 elems per (part)

  const int2 tile = tiles[blockIdx.y];
  const int e = tile.x;
  if (e < 0) return;
  const int s0   = tile.y;
  const int send = offsets[e + 1];
  // IS1: blockIdx.x = n-block (16). !IS1: x = part*8 + n-block (2x8).
  const int part = IS1 ? 0 : (blockIdx.x >> 3);
  const int n0   = (IS1 ? blockIdx.x : (blockIdx.x & 7)) * BN;
  const int kofs = part * 1024;       // k offset (elements)

  __shared__ unsigned short As[3][BM][BK];   // swizzled slot = s^((row>>1)&3)
  __shared__ unsigned short Bs[2][BN][BK];   // same swizzle
  __shared__ int rowsrc[BM];
  __shared__ int rowdst[BM];

  const int tid  = threadIdx.x;
  const int lane = tid & 63;
  const int wid  = tid >> 6;

  if (tid < BM) {
    int s = s0 + tid;
    bool v = s < send;
    int sc2 = v ? s : s0;
    if (IS1) {
      rowsrc[tid] = rows[sc2] >> 1;   // token id (K_=2)
      rowdst[tid] = v ? s : -1;       // h row (routed order)
    } else {
      rowsrc[tid] = sc2;              // h row
      rowdst[tid] = v ? rows[s] : -1; // pair id for scatter + score
    }
  }
  __syncthreads();

  // A staging (R11-verified): 2 x global_load_lds(16B)/wave, 16 rows each.
  // LDS dest linear; SOURCE slot pre-XOR'd with (row>>1)&3.
  const int arow16 = lane >> 2;                  // 0..15
  const int aslot  = (lane & 3) ^ ((arow16 >> 1) & 3);
  const unsigned short* gA[2];
#pragma unroll
  for (int i = 0; i < 2; ++i)
    gA[i] = A0 + (size_t)rowsrc[wid * 32 + i * 16 + arow16] * KD + kofs + aslot * 8;

  // B staging, line-efficient: thread t -> row t>>1 (0..127), 64B half (t&1).
  // Wave-instr = 32 consecutive rows x 128B full lines. 4 float4/thread/step.
  const int brow = tid >> 1, bhalf = tid & 1;
  const float* gB = W + (size_t)e * NN * KD + (size_t)(n0 + brow) * KD + kofs + bhalf * 16;

  const int wr = wid >> 1, wc = wid & 1;
  const int fr = lane & 15, fh = lane >> 4;

  f32x4 acc[4][4] = {};
  f32x4 breg0[4], breg1[4];

  auto issueA = [&](int buf, int kk) {
#pragma unroll
    for (int i = 0; i < 2; ++i)
      GLOAD16(gA[i] + kk, &As[buf][wid * 32 + i * 16][0]);
  };
  auto issueB = [&](f32x4* br, int kk) {
#pragma unroll
    for (int j = 0; j < 4; ++j)
      br[j] = *reinterpret_cast<const f32x4*>(gB + kk + j * 4);
  };
  // thread piece: row brow, 16 f32 at bhalf*16 -> 2 swizzled ushort8 slots.
  auto writeB = [&](int buf, const f32x4* br) {
#pragma unroll
    for (int j = 0; j < 2; ++j) {
      short8 v;
#pragma unroll
      for (int q = 0; q < 4; ++q) v[q]     = (short)f2bf(br[2*j][q]);
#pragma unroll
      for (int q = 0; q < 4; ++q) v[4 + q] = (short)f2bf(br[2*j+1][q]);
      int slot = (bhalf * 2 + j) ^ ((brow >> 1) & 3);
      *reinterpret_cast<short8*>(&Bs[buf][brow][slot * 8]) = v;
    }
  };
  auto compute = [&](int a3, int b2) {
    short8 af[4], bv[4];
#pragma unroll
    for (int mi = 0; mi < 4; ++mi) {
      const int row = wr * 64 + mi * 16 + fr;
      const int slot = fh ^ ((row >> 1) & 3);
      af[mi] = *reinterpret_cast<const short8*>(&As[a3][row][slot * 8]);
    }
#pragma unroll
    for (int ni = 0; ni < 4; ++ni) {
      const int row = wc * 64 + ni * 16 + fr;
      const int slot = fh ^ ((row >> 1) & 3);
      bv[ni] = *reinterpret_cast<const short8*>(&Bs[b2][row][slot * 8]);
    }
#pragma unroll
    for (int mi = 0; mi < 4; ++mi)
#pragma unroll
      for (int ni = 0; ni < 4; ++ni)
        acc[mi][ni] = __builtin_amdgcn_mfma_f32_16x16x32_bf16(
            af[mi], bv[ni], acc[mi][ni], 0, 0, 0);
  };

  // Prologue. Queue order: [A(0) 2, B(0) 4, A(1) 2].
  issueA(0, 0);
  issueB(breg0, 0);
  issueA(1, BK);

  // Per step t: waitv2 (tile t's A+B done; A(t+1) stays in flight) ->
  // writeB(t) -> issue B(t+1) (pre-barrier: extra flight) -> lgkm+barrier
  // (tile t visible; As[(t+2)%3] freed) -> issue A(t+2) -> compute(t).
  auto body = [&](int t, auto S3c, auto S2c) {
    constexpr int S3 = decltype(S3c)::value;
    constexpr int S2 = decltype(S2c)::value;
    f32x4* brCur  = S2 ? breg1 : breg0;
    f32x4* brNext = S2 ? breg0 : breg1;
    if (t + 1 < NT) waitv2(); else waitv0();
    writeB(S2, brCur);
    if (t + 1 < NT) issueB(brNext, (t + 1) * BK);
    lgkm0_barrier();
    if (t + 2 < NT) issueA((S3 + 2) % 3, (t + 2) * BK);
    compute(S3, S2);
  };
  for (int t = 0; t < NT; t += 6) {
    body(t, ic<0>{}, ic<0>{});
    if (t + 1 < NT) body(t + 1, ic<1>{}, ic<1>{});
    if (t + 2 < NT) body(t + 2, ic<2>{}, ic<0>{});
    if (t + 3 < NT) body(t + 3, ic<0>{}, ic<1>{});
    if (t + 4 < NT) body(t + 4, ic<1>{}, ic<0>{});
    if (t + 5 < NT) body(t + 5, ic<2>{}, ic<1>{});
  }

  // Epilogue. C/D map: row = (lane>>4)*4 + j, col = lane&15 (m89-verified).
  const float* biasE = bias + (size_t)e * NN + n0;
#pragma unroll
  for (int mi = 0; mi < 4; ++mi) {
#pragma unroll
    for (int j = 0; j < 4; ++j) {
      int rt  = wr * 64 + mi * 16 + fh * 4 + j;
      int dst = rowdst[rt];
      if (dst < 0) continue;
#pragma unroll
      for (int ni = 0; ni < 4; ++ni) {
        int col = wc * 64 + ni * 16 + fr;
        if (IS1) {
          float v = acc[mi][ni][j] + biasE[col];
          Hout[(size_t)dst * H_ + n0 + col] = f2bf(gelu_f(v));
        } else {
          // part 0 carries the bias; both parts scaled by gate score.
          float v = acc[mi][ni][j] + (part == 0 ? biasE[col] : 0.f);
          Yout[((size_t)part * NP_ + dst) * D_ + n0 + col] = v * score[dst];
        }
      }
    }
  }
}

__global__ void combine_kernel(const float* __restrict__ y,   // [2][NP_][D_]
                               float* __restrict__ out) {
  const int DQ = D_ / 4;
  int i = blockIdx.x * blockDim.x + threadIdx.x;   // [0, T_*D_/4)
  int t = i / DQ, d = i % DQ;
  const float4* y4 = reinterpret_cast<const float4*>(y);
  float4 r = make_float4(0.f, 0.f, 0.f, 0.f);
#pragma unroll
  for (int p = 0; p < 2; ++p)
#pragma unroll
    for (int k = 0; k < 2; ++k) {
      float4 a = y4[((size_t)p * NP_ + 2 * t + k) * DQ + d];
      r.x += a.x; r.y += a.y; r.z += a.z; r.w += a.w;
    }
  reinterpret_cast<float4*>(out)[i] = r;
}

extern "C" void kernel_launch(void* const* d_in, const int* in_sizes, int n_in,
                              void* d_out, int out_size, void* d_ws, size_t ws_size,
                              hipStream_t stream) {
  const float* inp    = (const float*)d_in[0];
  const int*   gidx   = (const int*)d_in[1];
  const float* gscore = (const float*)d_in[2];
  const float* w1     = (const float*)d_in[3];
  const float* b1     = (const float*)d_in[4];
  const float* w2     = (const float*)d_in[5];
  const float* b2     = (const float*)d_in[6];
  float* out = (float*)d_out;

  char* ws = (char*)d_ws;
  size_t o = 0;
  auto alloc = [&](size_t bytes) {
    void* p = ws + o;
    o = (o + bytes + 255) & ~(size_t)255;
    return p;
  };
  unsigned short* xb   = (unsigned short*)alloc((size_t)T_ * D_ * 2);
  unsigned short* hbuf = (unsigned short*)alloc((size_t)NP_ * H_ * 2);
  float*          ybuf = (float*)alloc((size_t)2 * NP_ * D_ * 4);
  int*            rows = (int*)alloc(NP_ * 4);
  int*         offsets = (int*)alloc((E_ + 1) * 4);
  int2*          tiles = (int2*)alloc(MTS_ * 8);

  cvt_kernel<<<dim3(512), dim3(256), 0, stream>>>(inp, xb, T_ * D_ / 4);
  route_kernel<<<dim3(1), dim3(256), 0, stream>>>(gidx, rows, offsets, tiles);

  moe_gemm<true><<<dim3(H_ / 128, MTS_), dim3(256), 0, stream>>>(
      xb, w1, b1, rows, offsets, tiles, gscore, hbuf, (float*)nullptr);
  moe_gemm<false><<<dim3(16, MTS_), dim3(256), 0, stream>>>(
      hbuf, w2, b2, rows, offsets, tiles, gscore, (unsigned short*)nullptr, ybuf);

  combine_kernel<<<dim3(T_ * D_ / 4 / 256), dim3(256), 0, stream>>>(ybuf, out);
}